// Round 1
// baseline (906.835 us; speedup 1.0000x reference)
//
#include <hip/hip_runtime.h>
#include <math.h>

#define EMB 300
#define HD  1024
#define VOC 50004
#define BB  64
#define LL  1024
#define NCH 16           // attention L-chunks (64 l's each)

// ---- workspace layout (float offsets) ----
#define WS_XT    0                         // x_T   [300][64]
#define WS_HT    (WS_XT + EMB*BB)          // h_T   [1024][64]
#define WS_HNT   (WS_HT + HD*BB)           // h_new_T [1024][64]
#define WS_WYB   (WS_HNT + HD*BB)          // Wy (b-major) [64][1024]
#define WS_CTXT  (WS_WYB + HD*BB)          // context_T [1024][64]
#define WS_FT    (WS_CTXT + HD*BB)         // fused_T [1024][64]
#define WS_SRAW  (WS_FT + HD*BB)           // raw scores [64][1024]
#define WS_MPART (WS_SRAW + BB*LL)         // [64][16]
#define WS_DPART (WS_MPART + BB*NCH)       // [64][16]
#define WS_CPART (WS_DPART + BB*NCH)       // [64][16][1024]
#define WS_LSE   (WS_CPART + BB*NCH*HD)    // [64]

#define OFF_H ((size_t)BB*VOC)
#define OFF_S (OFF_H + (size_t)BB*HD)

// K0: gather embedding into x_T[k][b]; transpose hidden into h_T[k][b]
__global__ __launch_bounds__(256) void k0_prep(
    const int* __restrict__ input, const float* __restrict__ hidden,
    const float* __restrict__ emb, float* __restrict__ ws)
{
  const int t = blockIdx.x * 256 + threadIdx.x;
  if (t < EMB * BB) {
    const int b = t & 63, k = t >> 6;
    ws[WS_XT + t] = emb[(size_t)input[b] * EMB + k];
  }
  const int u = t - EMB * BB;
  if (u >= 0 && u < HD * BB) {
    const int b = u & 63, k = u >> 6;
    ws[WS_HT + u] = hidden[(size_t)b * HD + k];
  }
}

// K1: GRU cell. thread = (lane=b, wave-uniform j). h_T chunked through LDS.
__global__ __launch_bounds__(256) void k1_gru(
    const float* __restrict__ w_ih, const float* __restrict__ w_hh,
    const float* __restrict__ b_ih, const float* __restrict__ b_hh,
    float* __restrict__ ws, float* __restrict__ out)
{
  __shared__ float tile[4096];
  const int tid = threadIdx.x;
  const int b = tid & 63;
  const int j = blockIdx.x * 4 + (tid >> 6);

  const float* xT = ws + WS_XT;
  const float* hT = ws + WS_HT;

  const float* wr = w_ih + (size_t)j * EMB;
  const float* wz = w_ih + (size_t)(HD + j) * EMB;
  const float* wn = w_ih + (size_t)(2 * HD + j) * EMB;
  float ar = 0.f, az = 0.f, an = 0.f;
  #pragma unroll 4
  for (int k = 0; k < EMB; ++k) {
    const float x = xT[k * 64 + b];
    ar = fmaf(wr[k], x, ar);
    az = fmaf(wz[k], x, az);
    an = fmaf(wn[k], x, an);
  }

  const float* vr = w_hh + (size_t)j * HD;
  const float* vz = w_hh + (size_t)(HD + j) * HD;
  const float* vn = w_hh + (size_t)(2 * HD + j) * HD;
  float hr = 0.f, hz = 0.f, hn = 0.f;
  for (int c = 0; c < 16; ++c) {
    __syncthreads();
    const float4* s4 = (const float4*)(hT + c * 4096);
    float4* t4 = (float4*)tile;
    #pragma unroll
    for (int q = 0; q < 4; ++q) t4[tid + 256 * q] = s4[tid + 256 * q];
    __syncthreads();
    const int kb = c * 64;
    #pragma unroll 8
    for (int kk = 0; kk < 64; ++kk) {
      const float hv = tile[kk * 64 + b];
      hr = fmaf(vr[kb + kk], hv, hr);
      hz = fmaf(vz[kb + kk], hv, hz);
      hn = fmaf(vn[kb + kk], hv, hn);
    }
  }

  const float r = 1.f / (1.f + __expf(-(ar + b_ih[j] + hr + b_hh[j])));
  const float z = 1.f / (1.f + __expf(-(az + b_ih[HD + j] + hz + b_hh[HD + j])));
  const float n = tanhf(an + b_ih[2 * HD + j] + r * (hn + b_hh[2 * HD + j]));
  const float h_old = hT[j * 64 + b];
  const float hnew = (1.f - z) * n + z * h_old;
  ws[WS_HNT + j * 64 + b] = hnew;
  out[OFF_H + (size_t)b * HD + j] = hnew;
}

// K2: Wy = h_new @ w_attn.T + b_attn, stored b-major for attention blocks
__global__ __launch_bounds__(256) void k2_wy(
    const float* __restrict__ w_attn, const float* __restrict__ b_attn,
    float* __restrict__ ws)
{
  __shared__ float tile[4096];
  const int tid = threadIdx.x;
  const int b = tid & 63;
  const int j = blockIdx.x * 4 + (tid >> 6);
  const float* hnT = ws + WS_HNT;
  const float* w = w_attn + (size_t)j * HD;
  float acc = b_attn[j];
  for (int c = 0; c < 16; ++c) {
    __syncthreads();
    const float4* s4 = (const float4*)(hnT + c * 4096);
    float4* t4 = (float4*)tile;
    #pragma unroll
    for (int q = 0; q < 4; ++q) t4[tid + 256 * q] = s4[tid + 256 * q];
    __syncthreads();
    const int kb = c * 64;
    #pragma unroll 8
    for (int kk = 0; kk < 64; ++kk)
      acc = fmaf(w[kb + kk], tile[kk * 64 + b], acc);
  }
  ws[WS_WYB + (size_t)b * HD + j] = acc;
}

// K3: flash-style attention partials. block = (chunk, b); wave handles 16 l's.
__global__ __launch_bounds__(256) void k3_attn(
    const float* __restrict__ src, const int* __restrict__ mask,
    float* __restrict__ ws)
{
  __shared__ float m_s[4], d_s[4];
  __shared__ float c_s[4 * 1024];
  const int tid = threadIdx.x;
  const int lane = tid & 63;
  const int wave = tid >> 6;
  const int b = blockIdx.y;
  const int chunk = blockIdx.x;

  float wy[16];
  {
    const float4* wb4 = (const float4*)(ws + WS_WYB + (size_t)b * HD);
    #pragma unroll
    for (int q = 0; q < 4; ++q) {
      const float4 t = wb4[lane * 4 + q];
      wy[q * 4 + 0] = t.x; wy[q * 4 + 1] = t.y;
      wy[q * 4 + 2] = t.z; wy[q * 4 + 3] = t.w;
    }
  }

  float c[16];
  #pragma unroll
  for (int u = 0; u < 16; ++u) c[u] = 0.f;
  float m_run = -INFINITY, d_run = 0.f;
  const int l0 = chunk * 64 + wave * 16;

  for (int i = 0; i < 16; ++i) {
    const int l = l0 + i;
    const float4* sp = (const float4*)(src + ((size_t)l * BB + b) * HD);
    float va[16];
    #pragma unroll
    for (int q = 0; q < 4; ++q) {
      const float4 t = sp[lane * 4 + q];
      va[q * 4 + 0] = t.x; va[q * 4 + 1] = t.y;
      va[q * 4 + 2] = t.z; va[q * 4 + 3] = t.w;
    }
    float s = 0.f;
    #pragma unroll
    for (int u = 0; u < 16; ++u) s = fmaf(va[u], wy[u], s);
    #pragma unroll
    for (int off = 32; off > 0; off >>= 1) s += __shfl_xor(s, off);

    const int msk = mask[(size_t)b * LL + l];
    if (lane == 0) ws[WS_SRAW + (size_t)b * LL + l] = msk ? -INFINITY : s;
    if (!msk) {                      // wave-uniform branch (s uniform after reduce)
      if (s > m_run) {
        const float sc = __expf(m_run - s);
        m_run = s;
        d_run *= sc;
        #pragma unroll
        for (int u = 0; u < 16; ++u) c[u] *= sc;
      }
      const float p = __expf(s - m_run);
      d_run += p;
      #pragma unroll
      for (int u = 0; u < 16; ++u) c[u] = fmaf(p, va[u], c[u]);
    }
  }

  if (lane == 0) { m_s[wave] = m_run; d_s[wave] = d_run; }
  #pragma unroll
  for (int u = 0; u < 16; ++u) c_s[wave * 1024 + lane * 16 + u] = c[u];
  __syncthreads();

  float M = -INFINITY;
  #pragma unroll
  for (int w = 0; w < 4; ++w) if (d_s[w] > 0.f) M = fmaxf(M, m_s[w]);
  float e[4]; float D = 0.f;
  #pragma unroll
  for (int w = 0; w < 4; ++w) {
    e[w] = (d_s[w] > 0.f) ? __expf(m_s[w] - M) : 0.f;
    D += d_s[w] * e[w];
  }
  const float4* cs4 = (const float4*)c_s;
  float4 a; a.x = a.y = a.z = a.w = 0.f;
  #pragma unroll
  for (int w = 0; w < 4; ++w) {
    const float4 cv = cs4[w * 256 + tid];
    a.x = fmaf(e[w], cv.x, a.x);
    a.y = fmaf(e[w], cv.y, a.y);
    a.z = fmaf(e[w], cv.z, a.z);
    a.w = fmaf(e[w], cv.w, a.w);
  }
  float4* cp4 = (float4*)(ws + WS_CPART + (size_t)(b * NCH + chunk) * HD);
  cp4[tid] = a;
  if (tid == 0) {
    ws[WS_MPART + b * NCH + chunk] = M;
    ws[WS_DPART + b * NCH + chunk] = D;
  }
}

// K3b: combine 16 chunk-partials per b; emit context_T and normalized scores
__global__ __launch_bounds__(256) void k3b_comb(
    float* __restrict__ ws, float* __restrict__ out)
{
  const int b = blockIdx.x;
  const int t = threadIdx.x;
  const float* mp = ws + WS_MPART + b * NCH;
  const float* dp = ws + WS_DPART + b * NCH;
  float M = -INFINITY;
  #pragma unroll
  for (int cc = 0; cc < NCH; ++cc) if (dp[cc] > 0.f) M = fmaxf(M, mp[cc]);
  float e[NCH]; float D = 0.f;
  #pragma unroll
  for (int cc = 0; cc < NCH; ++cc) {
    e[cc] = (dp[cc] > 0.f) ? __expf(mp[cc] - M) : 0.f;
    D += dp[cc] * e[cc];
  }
  const float invD = 1.f / D;
  #pragma unroll
  for (int q = 0; q < 4; ++q) {
    const int p = t + 256 * q;
    float a = 0.f;
    #pragma unroll
    for (int cc = 0; cc < NCH; ++cc)
      a = fmaf(ws[WS_CPART + (size_t)(b * NCH + cc) * HD + p], e[cc], a);
    ws[WS_CTXT + (size_t)p * 64 + b] = a * invD;
  }
  #pragma unroll
  for (int q = 0; q < 4; ++q) {
    const int l = t + 256 * q;
    const float s = ws[WS_SRAW + (size_t)b * LL + l];
    out[OFF_S + (size_t)b * LL + l] = __expf(s - M) * invD;  // exp(-inf)=0 for masked
  }
}

// K4: fused = tanh([context, h_new] @ w_lin.T + b_lin), stored transposed
__global__ __launch_bounds__(256) void k4_fused(
    const float* __restrict__ w_lin, const float* __restrict__ b_lin,
    float* __restrict__ ws)
{
  __shared__ float tile[4096];
  const int tid = threadIdx.x;
  const int b = tid & 63;
  const int j = blockIdx.x * 4 + (tid >> 6);
  float acc = b_lin[j];
  for (int ph = 0; ph < 2; ++ph) {
    const float* sp = ws + (ph == 0 ? WS_CTXT : WS_HNT);
    const float* w = w_lin + (size_t)j * (2 * HD) + ph * HD;
    for (int c = 0; c < 16; ++c) {
      __syncthreads();
      const float4* s4 = (const float4*)(sp + c * 4096);
      float4* t4 = (float4*)tile;
      #pragma unroll
      for (int q = 0; q < 4; ++q) t4[tid + 256 * q] = s4[tid + 256 * q];
      __syncthreads();
      const int kb = c * 64;
      #pragma unroll 8
      for (int kk = 0; kk < 64; ++kk)
        acc = fmaf(w[kb + kk], tile[kk * 64 + b], acc);
    }
  }
  ws[WS_FT + (size_t)j * 64 + b] = tanhf(acc);
}

// K5: logits = fused @ w_out.T + b_out. 64x64 tile, 4x4 micro-tile, K=1024.
#define BPAD 65
__global__ __launch_bounds__(256) void k5_logits(
    const float* __restrict__ w_out, const float* __restrict__ b_out,
    const float* __restrict__ ws, float* __restrict__ out)
{
  __shared__ float As[4096];
  __shared__ float Bs[64 * BPAD];
  const int tid = threadIdx.x;
  const int tv = tid & 15;
  const int tb = tid >> 4;
  const int vbase = blockIdx.x * 64;
  const float* fT = ws + WS_FT;

  const int vrow = tid >> 2;
  const int kq = tid & 3;
  int vglob = vbase + vrow;
  if (vglob >= VOC) vglob = VOC - 1;
  const float* wrow = w_out + (size_t)vglob * HD;

  float acc[4][4];
  #pragma unroll
  for (int i = 0; i < 4; ++i)
    #pragma unroll
    for (int jj = 0; jj < 4; ++jj) acc[i][jj] = 0.f;

  for (int c = 0; c < 16; ++c) {
    __syncthreads();
    const float4* a4 = (const float4*)(fT + c * 4096);
    float4* As4 = (float4*)As;
    #pragma unroll
    for (int q = 0; q < 4; ++q) As4[tid + 256 * q] = a4[tid + 256 * q];
    const float4* w4 = (const float4*)(wrow + c * 64 + kq * 16);
    #pragma unroll
    for (int q = 0; q < 4; ++q) {
      const float4 x = w4[q];
      const int kk = kq * 16 + q * 4;
      Bs[vrow * BPAD + kk + 0] = x.x;
      Bs[vrow * BPAD + kk + 1] = x.y;
      Bs[vrow * BPAD + kk + 2] = x.z;
      Bs[vrow * BPAD + kk + 3] = x.w;
    }
    __syncthreads();
    #pragma unroll 8
    for (int kk = 0; kk < 64; ++kk) {
      const float4 av = *(const float4*)&As[kk * 64 + tb * 4];
      const float avals[4] = { av.x, av.y, av.z, av.w };
      float bvals[4];
      #pragma unroll
      for (int vv = 0; vv < 4; ++vv) bvals[vv] = Bs[(tv * 4 + vv) * BPAD + kk];
      #pragma unroll
      for (int bb = 0; bb < 4; ++bb)
        #pragma unroll
        for (int vv = 0; vv < 4; ++vv)
          acc[bb][vv] = fmaf(avals[bb], bvals[vv], acc[bb][vv]);
    }
  }

  const int v0 = vbase + tv * 4;
  #pragma unroll
  for (int bb = 0; bb < 4; ++bb) {
    const int brow = tb * 4 + bb;
    float* orow = out + (size_t)brow * VOC;
    if (v0 + 3 < VOC) {
      float4 r;
      r.x = acc[bb][0] + b_out[v0 + 0];
      r.y = acc[bb][1] + b_out[v0 + 1];
      r.z = acc[bb][2] + b_out[v0 + 2];
      r.w = acc[bb][3] + b_out[v0 + 3];
      *(float4*)&orow[v0] = r;
    } else {
      for (int vv = 0; vv < 4; ++vv)
        if (v0 + vv < VOC) orow[v0 + vv] = acc[bb][vv] + b_out[v0 + vv];
    }
  }
}

// K6: per-row logsumexp over V
__global__ __launch_bounds__(256) void k6_lse(
    const float* __restrict__ out, float* __restrict__ ws)
{
  const int b = blockIdx.x, t = threadIdx.x;
  const float* row = out + (size_t)b * VOC;
  float m = -INFINITY, d = 0.f;
  for (int v = t; v < VOC; v += 256) {
    const float x = row[v];
    if (x > m) { d = d * __expf(m - x) + 1.f; m = x; }
    else d += __expf(x - m);
  }
  #pragma unroll
  for (int off = 32; off > 0; off >>= 1) {
    const float m2 = __shfl_xor(m, off);
    const float d2 = __shfl_xor(d, off);
    const float M = fmaxf(m, m2);
    d = d * __expf(m - M) + d2 * __expf(m2 - M);
    m = M;
  }
  __shared__ float ms[4], ds[4];
  if ((t & 63) == 0) { ms[t >> 6] = m; ds[t >> 6] = d; }
  __syncthreads();
  if (t == 0) {
    const float M = fmaxf(fmaxf(ms[0], ms[1]), fmaxf(ms[2], ms[3]));
    const float D = ds[0] * __expf(ms[0] - M) + ds[1] * __expf(ms[1] - M)
                  + ds[2] * __expf(ms[2] - M) + ds[3] * __expf(ms[3] - M);
    ws[WS_LSE + b] = M + __logf(D);
  }
}

// K7: logp = logits - lse[b]
__global__ __launch_bounds__(256) void k7_sub(
    float* __restrict__ out, const float* __restrict__ ws)
{
  const int b = blockIdx.y;
  const int v = blockIdx.x * 256 + threadIdx.x;
  if (v < VOC) out[(size_t)b * VOC + v] -= ws[WS_LSE + b];
}

extern "C" void kernel_launch(void* const* d_in, const int* in_sizes, int n_in,
                              void* d_out, int out_size, void* d_ws, size_t ws_size,
                              hipStream_t stream) {
  const int*   input  = (const int*)d_in[0];
  const float* hidden = (const float*)d_in[1];
  const float* src    = (const float*)d_in[2];
  const int*   mask   = (const int*)d_in[3];
  const float* emb    = (const float*)d_in[4];
  const float* w_ih   = (const float*)d_in[5];
  const float* w_hh   = (const float*)d_in[6];
  const float* b_ih   = (const float*)d_in[7];
  const float* b_hh   = (const float*)d_in[8];
  const float* w_attn = (const float*)d_in[9];
  const float* b_attn = (const float*)d_in[10];
  const float* w_lin  = (const float*)d_in[11];
  const float* b_lin  = (const float*)d_in[12];
  const float* w_out  = (const float*)d_in[13];
  const float* b_out  = (const float*)d_in[14];
  float* out = (float*)d_out;
  float* ws  = (float*)d_ws;

  k0_prep<<<331, 256, 0, stream>>>(input, hidden, emb, ws);
  k1_gru<<<256, 256, 0, stream>>>(w_ih, w_hh, b_ih, b_hh, ws, out);
  k2_wy<<<256, 256, 0, stream>>>(w_attn, b_attn, ws);
  k3_attn<<<dim3(NCH, BB), 256, 0, stream>>>(src, mask, ws);
  k3b_comb<<<BB, 256, 0, stream>>>(ws, out);
  k4_fused<<<256, 256, 0, stream>>>(w_lin, b_lin, ws);
  k5_logits<<<(VOC + 63) / 64, 256, 0, stream>>>(w_out, b_out, ws, out);
  k6_lse<<<BB, 256, 0, stream>>>(out, ws);
  k7_sub<<<dim3((VOC + 255) / 256, BB), 256, 0, stream>>>(out, ws);
}

// Round 2
// 695.684 us; speedup vs baseline: 1.3035x; 1.3035x over previous
//
#include <hip/hip_runtime.h>
#include <math.h>

#define EMB 300
#define HD  1024
#define VOC 50004
#define BB  64
#define LL  1024
#define NCH 16

typedef __attribute__((ext_vector_type(8))) short short8;
typedef __attribute__((ext_vector_type(4))) float f32x4;

// ---- workspace layout (float offsets) ----
#define WS_XT    0
#define WS_HT    (WS_XT + EMB*BB)
#define WS_HNT   (WS_HT + HD*BB)
#define WS_WYB   (WS_HNT + HD*BB)
#define WS_CTXT  (WS_WYB + HD*BB)
#define WS_AFR   (WS_CTXT + HD*BB)         // A-frag bf16 [32][4][64][8] = 32768 floats
#define WS_SRAW  (WS_AFR + HD*BB/2 + 64)
#define WS_MPART (WS_SRAW + BB*LL)
#define WS_DPART (WS_MPART + BB*NCH)
#define WS_CPART (WS_DPART + BB*NCH)
#define WS_LSE   (WS_CPART + BB*NCH*HD)    // [64][4][2]

#define OFF_H ((size_t)BB*VOC)
#define OFF_S (OFF_H + (size_t)BB*HD)

__device__ __forceinline__ unsigned short f2bf(float f) {
  union { float f; unsigned u; } v; v.f = f;
  unsigned r = v.u + 0x7fffu + ((v.u >> 16) & 1u);
  return (unsigned short)(r >> 16);
}

// K0: gather embedding into x_T[k][b]; transpose hidden into h_T[k][b]
__global__ __launch_bounds__(256) void k0_prep(
    const int* __restrict__ input, const float* __restrict__ hidden,
    const float* __restrict__ emb, float* __restrict__ ws)
{
  const int t = blockIdx.x * 256 + threadIdx.x;
  if (t < EMB * BB) {
    const int b = t & 63, k = t >> 6;
    ws[WS_XT + t] = emb[(size_t)input[b] * EMB + k];
  }
  const int u = t - EMB * BB;
  if (u >= 0 && u < HD * BB) {
    const int b = u & 63, k = u >> 6;
    ws[WS_HT + u] = hidden[(size_t)b * HD + k];
  }
}

// K1: GRU cell. block = one j (grid 1024); lanes = b; 4 waves split K.
__global__ __launch_bounds__(256) void k1_gru(
    const float* __restrict__ w_ih, const float* __restrict__ w_hh,
    const float* __restrict__ b_ih, const float* __restrict__ b_hh,
    float* __restrict__ ws, float* __restrict__ out)
{
  __shared__ float red[4][6][64];
  const int tid = threadIdx.x;
  const int b = tid & 63;
  const int w = tid >> 6;
  const int j = blockIdx.x;
  const float* xT = ws + WS_XT;
  const float* hT = ws + WS_HT;

  // input-hidden: K=300, 75 per wave
  const float* wr = w_ih + (size_t)j * EMB;
  const float* wz = w_ih + (size_t)(HD + j) * EMB;
  const float* wn = w_ih + (size_t)(2 * HD + j) * EMB;
  float ar = 0.f, az = 0.f, an = 0.f;
  #pragma unroll 5
  for (int kk = 0; kk < 75; ++kk) {
    const int k = w * 75 + kk;
    const float x = xT[k * 64 + b];
    ar = fmaf(wr[k], x, ar); az = fmaf(wz[k], x, az); an = fmaf(wn[k], x, an);
  }
  // hidden-hidden: K=1024, 256 per wave (64 float4)
  const float4* vr4 = (const float4*)(w_hh + (size_t)j * HD);
  const float4* vz4 = (const float4*)(w_hh + (size_t)(HD + j) * HD);
  const float4* vn4 = (const float4*)(w_hh + (size_t)(2 * HD + j) * HD);
  float hr = 0.f, hz = 0.f, hn = 0.f;
  #pragma unroll 4
  for (int kk = 0; kk < 64; ++kk) {
    const float4 r4 = vr4[w * 64 + kk];
    const float4 z4 = vz4[w * 64 + kk];
    const float4 n4 = vn4[w * 64 + kk];
    const int kb = (w * 256 + kk * 4) * 64 + b;
    const float h0 = hT[kb], h1 = hT[kb + 64], h2 = hT[kb + 128], h3 = hT[kb + 192];
    hr = fmaf(r4.x, h0, hr); hr = fmaf(r4.y, h1, hr); hr = fmaf(r4.z, h2, hr); hr = fmaf(r4.w, h3, hr);
    hz = fmaf(z4.x, h0, hz); hz = fmaf(z4.y, h1, hz); hz = fmaf(z4.z, h2, hz); hz = fmaf(z4.w, h3, hz);
    hn = fmaf(n4.x, h0, hn); hn = fmaf(n4.y, h1, hn); hn = fmaf(n4.z, h2, hn); hn = fmaf(n4.w, h3, hn);
  }
  red[w][0][b] = ar; red[w][1][b] = az; red[w][2][b] = an;
  red[w][3][b] = hr; red[w][4][b] = hz; red[w][5][b] = hn;
  __syncthreads();
  if (w == 0) {
    float s[6];
    #pragma unroll
    for (int q = 0; q < 6; ++q)
      s[q] = red[0][q][b] + red[1][q][b] + red[2][q][b] + red[3][q][b];
    const float r = 1.f / (1.f + __expf(-(s[0] + b_ih[j] + s[3] + b_hh[j])));
    const float z = 1.f / (1.f + __expf(-(s[1] + b_ih[HD + j] + s[4] + b_hh[HD + j])));
    const float n = tanhf(s[2] + b_ih[2 * HD + j] + r * (s[5] + b_hh[2 * HD + j]));
    const float h_old = hT[j * 64 + b];
    const float hnew = (1.f - z) * n + z * h_old;
    ws[WS_HNT + j * 64 + b] = hnew;
    out[OFF_H + (size_t)b * HD + j] = hnew;
  }
}

// K2: Wy = h_new @ w_attn.T + b_attn. block = one j; 4 waves split K.
__global__ __launch_bounds__(256) void k2_wy(
    const float* __restrict__ w_attn, const float* __restrict__ b_attn,
    float* __restrict__ ws)
{
  __shared__ float red[4][64];
  const int tid = threadIdx.x;
  const int b = tid & 63;
  const int w = tid >> 6;
  const int j = blockIdx.x;
  const float* hnT = ws + WS_HNT;
  const float4* w4 = (const float4*)(w_attn + (size_t)j * HD);
  float acc = 0.f;
  #pragma unroll 4
  for (int kk = 0; kk < 64; ++kk) {
    const float4 a4 = w4[w * 64 + kk];
    const int kb = (w * 256 + kk * 4) * 64 + b;
    acc = fmaf(a4.x, hnT[kb], acc);
    acc = fmaf(a4.y, hnT[kb + 64], acc);
    acc = fmaf(a4.z, hnT[kb + 128], acc);
    acc = fmaf(a4.w, hnT[kb + 192], acc);
  }
  red[w][b] = acc;
  __syncthreads();
  if (w == 0)
    ws[WS_WYB + (size_t)b * HD + j] = red[0][b] + red[1][b] + red[2][b] + red[3][b] + b_attn[j];
}

// K3: flash attention partials; lane-contiguous float4 loads.
__global__ __launch_bounds__(256) void k3_attn(
    const float* __restrict__ src, const int* __restrict__ mask,
    float* __restrict__ ws)
{
  __shared__ float m_s[4], d_s[4];
  __shared__ float c_s[4 * 1024];
  const int tid = threadIdx.x;
  const int lane = tid & 63;
  const int wave = tid >> 6;
  const int b = blockIdx.y;
  const int chunk = blockIdx.x;

  float4 wy[4];
  const float4* wb4 = (const float4*)(ws + WS_WYB + (size_t)b * HD);
  #pragma unroll
  for (int q = 0; q < 4; ++q) wy[q] = wb4[q * 64 + lane];

  float4 c[4];
  #pragma unroll
  for (int q = 0; q < 4; ++q) { c[q].x = 0.f; c[q].y = 0.f; c[q].z = 0.f; c[q].w = 0.f; }
  float m_run = -INFINITY, d_run = 0.f;
  const int l0 = chunk * 64 + wave * 16;

  for (int i = 0; i < 16; ++i) {
    const int l = l0 + i;
    const float4* sp4 = (const float4*)(src + ((size_t)l * BB + b) * HD);
    float4 va[4];
    #pragma unroll
    for (int q = 0; q < 4; ++q) va[q] = sp4[q * 64 + lane];
    float s = 0.f;
    #pragma unroll
    for (int q = 0; q < 4; ++q) {
      s = fmaf(va[q].x, wy[q].x, s); s = fmaf(va[q].y, wy[q].y, s);
      s = fmaf(va[q].z, wy[q].z, s); s = fmaf(va[q].w, wy[q].w, s);
    }
    #pragma unroll
    for (int off = 32; off > 0; off >>= 1) s += __shfl_xor(s, off);

    const int msk = mask[(size_t)b * LL + l];
    if (lane == 0) ws[WS_SRAW + (size_t)b * LL + l] = msk ? -INFINITY : s;
    if (!msk) {
      if (s > m_run) {
        const float sc = __expf(m_run - s);
        m_run = s; d_run *= sc;
        #pragma unroll
        for (int q = 0; q < 4; ++q) {
          c[q].x *= sc; c[q].y *= sc; c[q].z *= sc; c[q].w *= sc;
        }
      }
      const float p = __expf(s - m_run);
      d_run += p;
      #pragma unroll
      for (int q = 0; q < 4; ++q) {
        c[q].x = fmaf(p, va[q].x, c[q].x); c[q].y = fmaf(p, va[q].y, c[q].y);
        c[q].z = fmaf(p, va[q].z, c[q].z); c[q].w = fmaf(p, va[q].w, c[q].w);
      }
    }
  }

  if (lane == 0) { m_s[wave] = m_run; d_s[wave] = d_run; }
  float4* cs4 = (float4*)c_s;
  #pragma unroll
  for (int q = 0; q < 4; ++q) cs4[wave * 256 + q * 64 + lane] = c[q];
  __syncthreads();

  float M = -INFINITY;
  #pragma unroll
  for (int w = 0; w < 4; ++w) if (d_s[w] > 0.f) M = fmaxf(M, m_s[w]);
  float e[4]; float D = 0.f;
  #pragma unroll
  for (int w = 0; w < 4; ++w) {
    e[w] = (d_s[w] > 0.f) ? __expf(m_s[w] - M) : 0.f;
    D += d_s[w] * e[w];
  }
  float4 a; a.x = a.y = a.z = a.w = 0.f;
  #pragma unroll
  for (int w = 0; w < 4; ++w) {
    const float4 cv = cs4[w * 256 + tid];
    a.x = fmaf(e[w], cv.x, a.x); a.y = fmaf(e[w], cv.y, a.y);
    a.z = fmaf(e[w], cv.z, a.z); a.w = fmaf(e[w], cv.w, a.w);
  }
  ((float4*)(ws + WS_CPART))[(size_t)(b * NCH + chunk) * 256 + tid] = a;
  if (tid == 0) {
    ws[WS_MPART + b * NCH + chunk] = M;
    ws[WS_DPART + b * NCH + chunk] = D;
  }
}

// K3b: combine chunk partials (slot-permuted CPART); emit context_T + scores
__global__ __launch_bounds__(256) void k3b_comb(
    float* __restrict__ ws, float* __restrict__ out)
{
  const int b = blockIdx.x;
  const int t = threadIdx.x;
  const float* mp = ws + WS_MPART + b * NCH;
  const float* dp = ws + WS_DPART + b * NCH;
  float M = -INFINITY;
  #pragma unroll
  for (int cc = 0; cc < NCH; ++cc) if (dp[cc] > 0.f) M = fmaxf(M, mp[cc]);
  float e[NCH]; float D = 0.f;
  #pragma unroll
  for (int cc = 0; cc < NCH; ++cc) {
    e[cc] = (dp[cc] > 0.f) ? __expf(mp[cc] - M) : 0.f;
    D += dp[cc] * e[cc];
  }
  const float invD = 1.f / D;
  const float4* cp4 = (const float4*)(ws + WS_CPART);
  float4 a; a.x = a.y = a.z = a.w = 0.f;
  #pragma unroll
  for (int cc = 0; cc < NCH; ++cc) {
    const float4 cv = cp4[(size_t)(b * NCH + cc) * 256 + t];
    a.x = fmaf(e[cc], cv.x, a.x); a.y = fmaf(e[cc], cv.y, a.y);
    a.z = fmaf(e[cc], cv.z, a.z); a.w = fmaf(e[cc], cv.w, a.w);
  }
  const int e0 = (t >> 6) * 256 + (t & 63) * 4;   // element index of slot t
  ws[WS_CTXT + (size_t)(e0 + 0) * 64 + b] = a.x * invD;
  ws[WS_CTXT + (size_t)(e0 + 1) * 64 + b] = a.y * invD;
  ws[WS_CTXT + (size_t)(e0 + 2) * 64 + b] = a.z * invD;
  ws[WS_CTXT + (size_t)(e0 + 3) * 64 + b] = a.w * invD;
  #pragma unroll
  for (int q = 0; q < 4; ++q) {
    const int l = t + 256 * q;
    const float s = ws[WS_SRAW + (size_t)b * LL + l];
    out[OFF_S + (size_t)b * LL + l] = __expf(s - M) * invD;
  }
}

// K4: fused = tanh([ctx,h'] @ w_lin.T + b_lin) -> bf16 MFMA A-fragment layout
__global__ __launch_bounds__(256) void k4_fused(
    const float* __restrict__ w_lin, const float* __restrict__ b_lin,
    float* __restrict__ ws)
{
  __shared__ float red[4][64];
  const int tid = threadIdx.x;
  const int b = tid & 63;
  const int w = tid >> 6;
  const int j = blockIdx.x;
  const float4* wl4 = (const float4*)(w_lin + (size_t)j * (2 * HD));
  const float* act = (w < 2) ? (ws + WS_CTXT) : (ws + WS_HNT);
  float acc = 0.f;
  #pragma unroll 4
  for (int kk = 0; kk < 128; ++kk) {
    const float4 a4 = wl4[w * 128 + kk];
    const int kb = ((w & 1) * 512 + kk * 4) * 64 + b;
    acc = fmaf(a4.x, act[kb], acc);
    acc = fmaf(a4.y, act[kb + 64], acc);
    acc = fmaf(a4.z, act[kb + 128], acc);
    acc = fmaf(a4.w, act[kb + 192], acc);
  }
  red[w][b] = acc;
  __syncthreads();
  if (w == 0) {
    const float f = tanhf(red[0][b] + red[1][b] + red[2][b] + red[3][b] + b_lin[j]);
    unsigned short* af = (unsigned short*)(ws + WS_AFR);
    const int t = j >> 5, kk = j & 31;
    const int lp = (b & 15) + 16 * (kk >> 3);
    const int mt = b >> 4;
    af[(((t * 4 + mt) * 64 + lp) << 3) + (kk & 7)] = f2bf(f);
  }
}

// K5: logits via bf16 MFMA 16x16x32. tile 64b x 128v, grid 391.
__global__ __launch_bounds__(256) void k5_logits(
    const float* __restrict__ w_out, const float* __restrict__ b_out,
    const float* __restrict__ ws, float* __restrict__ out)
{
  __shared__ unsigned short Bs[8 * 64 * 8];  // 8KB: [vt][lane][j]
  const int tid = threadIdx.x;
  const int lane = tid & 63;
  const int w = tid >> 6;
  const int vbase = blockIdx.x * 128;
  const unsigned short* af = (const unsigned short*)(ws + WS_AFR);

  f32x4 acc[4][2];
  #pragma unroll
  for (int mt = 0; mt < 4; ++mt)
    #pragma unroll
    for (int nb = 0; nb < 2; ++nb)
      acc[mt][nb] = (f32x4){0.f, 0.f, 0.f, 0.f};

  for (int t = 0; t < 32; ++t) {
    const int k0 = t * 32;
    __syncthreads();
    #pragma unroll
    for (int h = 0; h < 4; ++h) {
      const int idx = tid + 256 * h;
      const int vl = idx >> 3, s = idx & 7;
      int vg = vbase + vl; if (vg >= VOC) vg = VOC - 1;
      const float4 x = *(const float4*)(w_out + (size_t)vg * HD + k0 + s * 4);
      const int vt = vl >> 4;
      const int lp = (vl & 15) + 16 * (s >> 1);
      unsigned u0 = (unsigned)f2bf(x.x) | ((unsigned)f2bf(x.y) << 16);
      unsigned u1 = (unsigned)f2bf(x.z) | ((unsigned)f2bf(x.w) << 16);
      uint2* dst = (uint2*)&Bs[((vt * 64 + lp) << 3) + (s & 1) * 4];
      *dst = make_uint2(u0, u1);
    }
    __syncthreads();
    short8 a[4];
    #pragma unroll
    for (int mt = 0; mt < 4; ++mt)
      a[mt] = *(const short8*)(af + (((t * 4 + mt) * 64 + lane) << 3));
    short8 bf[2];
    #pragma unroll
    for (int nb = 0; nb < 2; ++nb)
      bf[nb] = *(const short8*)&Bs[(((w * 2 + nb) * 64 + lane)) << 3];
    #pragma unroll
    for (int mt = 0; mt < 4; ++mt)
      #pragma unroll
      for (int nb = 0; nb < 2; ++nb)
        acc[mt][nb] = __builtin_amdgcn_mfma_f32_16x16x32_bf16(a[mt], bf[nb], acc[mt][nb], 0, 0, 0);
  }

  #pragma unroll
  for (int nb = 0; nb < 2; ++nb) {
    const int v = vbase + (w * 2 + nb) * 16 + (lane & 15);
    if (v < VOC) {
      const float bias = b_out[v];
      #pragma unroll
      for (int mt = 0; mt < 4; ++mt) {
        #pragma unroll
        for (int r = 0; r < 4; ++r) {
          const int brow = mt * 16 + (lane >> 4) * 4 + r;
          out[(size_t)brow * VOC + v] = acc[mt][nb][r] + bias;
        }
      }
    }
  }
}

// K6: partial logsumexp; grid (4, B), each block V/4 slice
__global__ __launch_bounds__(256) void k6_lse(
    const float* __restrict__ out, float* __restrict__ ws)
{
  const int chunk = blockIdx.x, b = blockIdx.y, t = threadIdx.x;
  const int base = chunk * 12501;
  const float* row = out + (size_t)b * VOC;
  float m = -INFINITY, d = 0.f;
  for (int v = base + t; v < base + 12501; v += 256) {
    const float x = row[v];
    if (x > m) { d = d * __expf(m - x) + 1.f; m = x; }
    else d += __expf(x - m);
  }
  #pragma unroll
  for (int off = 32; off > 0; off >>= 1) {
    const float m2 = __shfl_xor(m, off);
    const float d2 = __shfl_xor(d, off);
    const float M = fmaxf(m, m2);
    d = d * __expf(m - M) + d2 * __expf(m2 - M);
    m = M;
  }
  __shared__ float ms[4], ds[4];
  if ((t & 63) == 0) { ms[t >> 6] = m; ds[t >> 6] = d; }
  __syncthreads();
  if (t == 0) {
    const float M = fmaxf(fmaxf(ms[0], ms[1]), fmaxf(ms[2], ms[3]));
    const float D = ds[0] * __expf(ms[0] - M) + ds[1] * __expf(ms[1] - M)
                  + ds[2] * __expf(ms[2] - M) + ds[3] * __expf(ms[3] - M);
    ws[WS_LSE + (b * 4 + chunk) * 2] = M;
    ws[WS_LSE + (b * 4 + chunk) * 2 + 1] = D;
  }
}

// K7: combine partial lse + subtract
__global__ __launch_bounds__(256) void k7_sub(
    float* __restrict__ out, const float* __restrict__ ws)
{
  const int b = blockIdx.y;
  const int v = blockIdx.x * 256 + threadIdx.x;
  const float* p = ws + WS_LSE + b * 8;
  float M = fmaxf(fmaxf(p[0], p[2]), fmaxf(p[4], p[6]));
  float D = p[1] * __expf(p[0] - M) + p[3] * __expf(p[2] - M)
          + p[5] * __expf(p[4] - M) + p[7] * __expf(p[6] - M);
  const float lse = M + __logf(D);
  if (v < VOC) out[(size_t)b * VOC + v] -= lse;
}

extern "C" void kernel_launch(void* const* d_in, const int* in_sizes, int n_in,
                              void* d_out, int out_size, void* d_ws, size_t ws_size,
                              hipStream_t stream) {
  const int*   input  = (const int*)d_in[0];
  const float* hidden = (const float*)d_in[1];
  const float* src    = (const float*)d_in[2];
  const int*   mask   = (const int*)d_in[3];
  const float* emb    = (const float*)d_in[4];
  const float* w_ih   = (const float*)d_in[5];
  const float* w_hh   = (const float*)d_in[6];
  const float* b_ih   = (const float*)d_in[7];
  const float* b_hh   = (const float*)d_in[8];
  const float* w_attn = (const float*)d_in[9];
  const float* b_attn = (const float*)d_in[10];
  const float* w_lin  = (const float*)d_in[11];
  const float* b_lin  = (const float*)d_in[12];
  const float* w_out  = (const float*)d_in[13];
  const float* b_out  = (const float*)d_in[14];
  float* out = (float*)d_out;
  float* ws  = (float*)d_ws;

  k0_prep<<<331, 256, 0, stream>>>(input, hidden, emb, ws);
  k1_gru<<<1024, 256, 0, stream>>>(w_ih, w_hh, b_ih, b_hh, ws, out);
  k2_wy<<<1024, 256, 0, stream>>>(w_attn, b_attn, ws);
  k3_attn<<<dim3(NCH, BB), 256, 0, stream>>>(src, mask, ws);
  k3b_comb<<<BB, 256, 0, stream>>>(ws, out);
  k4_fused<<<1024, 256, 0, stream>>>(w_lin, b_lin, ws);
  k5_logits<<<(VOC + 127) / 128, 256, 0, stream>>>(w_out, b_out, ws, out);
  k6_lse<<<dim3(4, BB), 256, 0, stream>>>(out, ws);
  k7_sub<<<dim3((VOC + 255) / 256, BB), 256, 0, stream>>>(out, ws);
}